// Round 2
// baseline (148.942 us; speedup 1.0000x reference)
//
#include <hip/hip_runtime.h>

typedef unsigned short u16;
typedef unsigned int u32;
typedef __attribute__((ext_vector_type(8))) short short8;
typedef __attribute__((ext_vector_type(4))) float f32x4;

__device__ __forceinline__ float bl(u32 u){ return __builtin_bit_cast(float, u << 16); }
__device__ __forceinline__ float bh(u32 u){ return __builtin_bit_cast(float, u & 0xffff0000u); }
__device__ __forceinline__ float bf2f(u16 h){ return __builtin_bit_cast(float, ((u32)h) << 16); }
__device__ __forceinline__ u16 f2bf(float f){
  u32 u = __builtin_bit_cast(u32, f);
  u32 r = u + 0x7fffu + ((u >> 16) & 1u);
  return (u16)(r >> 16);
}

// ------- Kernel 0: x fp32 [b][c][hw] -> XTh/XTl bf16 hi/lo split, pixel-major [pix][c] -------
__global__ __launch_bounds__(256) void split_in(const float* __restrict__ x,
                                                u16* __restrict__ XTh,
                                                u16* __restrict__ XTl)
{
  __shared__ float tile[64 * 68];
  int t = threadIdx.x;
  int hw0 = blockIdx.x * 64, c0 = blockIdx.y * 64, b = blockIdx.z;
  {
    int cl = t >> 2, seg = (t & 3) * 16;
    const float* src = x + (b * 256 + c0 + cl) * 4096 + hw0 + seg;
    float4 v0 = ((const float4*)src)[0];
    float4 v1 = ((const float4*)src)[1];
    float4 v2 = ((const float4*)src)[2];
    float4 v3 = ((const float4*)src)[3];
    float* d = tile + cl * 68 + seg;
    ((float4*)d)[0] = v0; ((float4*)d)[1] = v1;
    ((float4*)d)[2] = v2; ((float4*)d)[3] = v3;
  }
  __syncthreads();
  {
    int hwl = t >> 2, cs = (t & 3) * 16;
    u32 ph[8], pl[8];
    #pragma unroll
    for (int e = 0; e < 8; ++e) {
      float v0 = tile[(cs + 2 * e) * 68 + hwl];
      float v1 = tile[(cs + 2 * e + 1) * 68 + hwl];
      u16 h0 = f2bf(v0), h1 = f2bf(v1);
      u16 l0 = f2bf(v0 - bf2f(h0)), l1 = f2bf(v1 - bf2f(h1));
      ph[e] = (u32)h0 | ((u32)h1 << 16);
      pl[e] = (u32)l0 | ((u32)l1 << 16);
    }
    int off = (b * 4096 + hw0 + hwl) * 256 + c0 + cs;
    *(uint4*)(XTh + off)     = make_uint4(ph[0], ph[1], ph[2], ph[3]);
    *(uint4*)(XTh + off + 8) = make_uint4(ph[4], ph[5], ph[6], ph[7]);
    *(uint4*)(XTl + off)     = make_uint4(pl[0], pl[1], pl[2], pl[3]);
    *(uint4*)(XTl + off + 8) = make_uint4(pl[4], pl[5], pl[6], pl[7]);
  }
}

// ------- Kernel 0b: w1|w2|w3 fp32 [o][c] -> Wh/Wl bf16 hi/lo -------
__global__ __launch_bounds__(256) void wsplit(const float* __restrict__ w1,
                                              const float* __restrict__ w2,
                                              const float* __restrict__ w3,
                                              u16* __restrict__ Wh,
                                              u16* __restrict__ Wl)
{
  int i = (blockIdx.x * 256 + threadIdx.x) * 4;
  int z = i >> 16, off = i & 65535;
  const float* w = (z == 0) ? w1 : ((z == 1) ? w2 : w3);
  float4 v = *(const float4*)(w + off);
  u16 h0 = f2bf(v.x), h1 = f2bf(v.y), h2 = f2bf(v.z), h3 = f2bf(v.w);
  u16 l0 = f2bf(v.x - bf2f(h0)), l1 = f2bf(v.y - bf2f(h1));
  u16 l2 = f2bf(v.z - bf2f(h2)), l3 = f2bf(v.w - bf2f(h3));
  uint2 hv; hv.x = (u32)h0 | ((u32)h1 << 16); hv.y = (u32)h2 | ((u32)h3 << 16);
  uint2 lv; lv.x = (u32)l0 | ((u32)l1 << 16); lv.y = (u32)l2 | ((u32)l3 << 16);
  *(uint2*)(Wh + i) = hv;
  *(uint2*)(Wl + i) = lv;
}

// ------- Kernel 1: q/k via 3-pass split-bf16 MFMA -> hi/lo bf16 pixel-major;
//         v via 1-pass -> bf16 c-major. grid (128, 2, 3). -------
#define LSTR 40
__global__ __launch_bounds__(256) void qkv_gemm(const u16* __restrict__ XTh,
                                                const u16* __restrict__ XTl,
                                                const u16* __restrict__ Wh,
                                                const u16* __restrict__ Wl,
                                                u16* __restrict__ qh_, u16* __restrict__ ql_,
                                                u16* __restrict__ kh_, u16* __restrict__ kl_,
                                                u16* __restrict__ vo)
{
  __shared__ u16 lAh[128 * LSTR];
  __shared__ u16 lBh[128 * LSTR];
  __shared__ u16 lAl[128 * LSTR];
  __shared__ u16 lBl[128 * LSTR];
  int z = blockIdx.z;
  int t = threadIdx.x;
  int lane = t & 63, wv = t >> 6;
  int ln15 = lane & 15, q = lane >> 4;
  int pix0 = blockIdx.x * 128;
  int o0 = blockIdx.y * 128;
  int pw = (wv >> 1) * 64, ow = (wv & 1) * 64;
  f32x4 acc[4][4];
  #pragma unroll
  for (int i = 0; i < 4; ++i)
    #pragma unroll
    for (int j = 0; j < 4; ++j)
      acc[i][j] = (f32x4){0.f, 0.f, 0.f, 0.f};

  int srow = t >> 1;
  int sseg = (t & 1) * 16;
  const u16* gAh = XTh + (pix0 + srow) * 256 + sseg;
  const u16* gAl = XTl + (pix0 + srow) * 256 + sseg;
  const u16* gBh = Wh + z * 65536 + (o0 + srow) * 256 + sseg;
  const u16* gBl = Wl + z * 65536 + (o0 + srow) * 256 + sseg;
  u16* sAh = lAh + srow * LSTR + sseg;
  u16* sAl = lAl + srow * LSTR + sseg;
  u16* sBh = lBh + srow * LSTR + sseg;
  u16* sBl = lBl + srow * LSTR + sseg;

  for (int kc = 0; kc < 256; kc += 32) {
    uint4 ah0 = *(const uint4*)(gAh + kc);
    uint4 ah1 = *(const uint4*)(gAh + kc + 8);
    uint4 bh0 = *(const uint4*)(gBh + kc);
    uint4 bh1 = *(const uint4*)(gBh + kc + 8);
    uint4 al0 = make_uint4(0,0,0,0), al1 = make_uint4(0,0,0,0);
    uint4 bl0 = make_uint4(0,0,0,0), bl1 = make_uint4(0,0,0,0);
    if (z < 2) {
      al0 = *(const uint4*)(gAl + kc);
      al1 = *(const uint4*)(gAl + kc + 8);
      bl0 = *(const uint4*)(gBl + kc);
      bl1 = *(const uint4*)(gBl + kc + 8);
    }
    __syncthreads();
    *(uint4*)sAh = ah0; *(uint4*)(sAh + 8) = ah1;
    *(uint4*)sBh = bh0; *(uint4*)(sBh + 8) = bh1;
    if (z < 2) {
      *(uint4*)sAl = al0; *(uint4*)(sAl + 8) = al1;
      *(uint4*)sBl = bl0; *(uint4*)(sBl + 8) = bl1;
    }
    __syncthreads();
    short8 afh[4], bfh[4];
    #pragma unroll
    for (int i = 0; i < 4; ++i)
      afh[i] = *(const short8*)(lAh + (pw + i * 16 + ln15) * LSTR + q * 8);
    #pragma unroll
    for (int j = 0; j < 4; ++j)
      bfh[j] = *(const short8*)(lBh + (ow + j * 16 + ln15) * LSTR + q * 8);
    #pragma unroll
    for (int i = 0; i < 4; ++i)
      #pragma unroll
      for (int j = 0; j < 4; ++j)
        acc[i][j] = __builtin_amdgcn_mfma_f32_16x16x32_bf16(afh[i], bfh[j], acc[i][j], 0, 0, 0);
    if (z < 2) {
      short8 afl[4], bfl[4];
      #pragma unroll
      for (int i = 0; i < 4; ++i)
        afl[i] = *(const short8*)(lAl + (pw + i * 16 + ln15) * LSTR + q * 8);
      #pragma unroll
      for (int j = 0; j < 4; ++j)
        bfl[j] = *(const short8*)(lBl + (ow + j * 16 + ln15) * LSTR + q * 8);
      #pragma unroll
      for (int i = 0; i < 4; ++i)
        #pragma unroll
        for (int j = 0; j < 4; ++j) {
          acc[i][j] = __builtin_amdgcn_mfma_f32_16x16x32_bf16(afh[i], bfl[j], acc[i][j], 0, 0, 0);
          acc[i][j] = __builtin_amdgcn_mfma_f32_16x16x32_bf16(afl[i], bfh[j], acc[i][j], 0, 0, 0);
        }
    }
  }

  // D: m(pixel) = pw + i*16 + q*4 + r, n(o) = ow + j*16 + ln15
  if (z == 2) {
    // v: c-major [o][pix]; 4 acc regs = 4 consecutive pixels -> packed uint2 store
    #pragma unroll
    for (int i = 0; i < 4; ++i) {
      int pixb = pix0 + pw + i * 16 + q * 4;
      #pragma unroll
      for (int j = 0; j < 4; ++j) {
        int o = o0 + ow + j * 16 + ln15;
        u32 p0 = (u32)f2bf(acc[i][j][0]) | ((u32)f2bf(acc[i][j][1]) << 16);
        u32 p1 = (u32)f2bf(acc[i][j][2]) | ((u32)f2bf(acc[i][j][3]) << 16);
        uint2 pv; pv.x = p0; pv.y = p1;
        *(uint2*)(vo + o * 16384 + pixb) = pv;
      }
    }
  } else {
    u16* dsth = (z == 0) ? qh_ : kh_;
    u16* dstl = (z == 0) ? ql_ : kl_;
    #pragma unroll
    for (int i = 0; i < 4; ++i) {
      #pragma unroll
      for (int r = 0; r < 4; ++r) {
        int pix = pix0 + pw + i * 16 + q * 4 + r;
        int ob = o0 + ow + ln15;
        #pragma unroll
        for (int j = 0; j < 4; ++j) {
          float vv = acc[i][j][r];
          u16 hh = f2bf(vv);
          u16 ll = f2bf(vv - bf2f(hh));
          dsth[pix * 256 + ob + j * 16] = hh;
          dstl[pix * 256 + ob + j * 16] = ll;
        }
      }
    }
  }
}

// ------- Kernel 2: banded-MFMA local attention. Block = quarter image row (16 px). -------
// Branch-free load path: neighbor-row index clamped to [0,63] so every load is issued
// unconditionally (exec-masked ternaries only); dh loops fully unrolled -> deep MLP.
// OOB contributions discarded at the consumer (scatter skip / zeroed A-operand).
__global__ __launch_bounds__(256, 4) void attn(const u16* __restrict__ qh_,
                                               const u16* __restrict__ ql_,
                                               const u16* __restrict__ kh_,
                                               const u16* __restrict__ kl_,
                                               const u16* __restrict__ vo,
                                               float* __restrict__ out)
{
  __shared__ float lg2[2][16][57];       // logits, split by cc-half (summed in softmax)
  __shared__ u16 pb[7][16][40];          // banded prob B-operand [dh][m'][n'(pad 40)]

  const int t = threadIdx.x;
  const int lane = t & 63, wv = t >> 6;
  const int l15 = lane & 15, q4 = lane >> 4;
  // 1024 blocks, 8 XCDs: bijective chunked remap (1024 % 8 == 0)
  const int bid = ((int)blockIdx.x & 7) * 128 + ((int)blockIdx.x >> 3);
  const int quarter = bid & 3;
  const int row = bid >> 2;               // b*64 + h
  const int b = row >> 6, h = row & 63;
  const int wbase = quarter * 16;         // m-tile w start

  for (int i = t; i < 2 * 16 * 57; i += 256) ((float*)lg2)[i] = 0.f;
  for (int i = t; i < 2240; i += 256) ((u32*)pb)[i] = 0u;
  __syncthreads();

  const short8 zf = {0, 0, 0, 0, 0, 0, 0, 0};

  // ---------- phase 1: logits ----------
  {
    const int win = wv & 1, ch = wv >> 1;      // wave -> (n-window, c-half)
    short8 qfh[4], qfl[4];
    {
      const int pix = row * 64 + wbase + l15;  // A: m = l15 (query pixel)
      const u16* qhp = qh_ + pix * 256;
      const u16* qlp = ql_ + pix * 256;
      #pragma unroll
      for (int u = 0; u < 4; ++u) {
        const int c0 = (ch * 4 + u) * 32 + q4 * 8;
        qfh[u] = *(const short8*)(qhp + c0);
        qfl[u] = *(const short8*)(qlp + c0);
      }
    }
    const int wn = wbase - 8 + win * 16 + l15; // neighbor w (B: n = l15)
    const bool ok = (wn >= 0) && (wn < 64);
    __builtin_amdgcn_s_setprio(1);
    #pragma unroll
    for (int dh = 0; dh < 7; ++dh) {
      const int rdh = h + dh - 3;
      const bool rok = (rdh >= 0) && (rdh < 64);
      const int rdhc = rdh < 0 ? 0 : (rdh > 63 ? 63 : rdh);   // clamped -> address always valid
      const int rp = (b * 64 + rdhc) * 64;
      const u16* k0h = kh_ + (rp + wn) * 256;
      const u16* k0l = kl_ + (rp + wn) * 256;
      f32x4 a0 = {0.f, 0.f, 0.f, 0.f};
      #pragma unroll
      for (int u = 0; u < 4; ++u) {
        const int c0 = (ch * 4 + u) * 32 + q4 * 8;
        short8 b0h = ok ? *(const short8*)(k0h + c0) : zf;
        short8 b0l = ok ? *(const short8*)(k0l + c0) : zf;
        a0 = __builtin_amdgcn_mfma_f32_16x16x32_bf16(qfh[u], b0h, a0, 0, 0, 0);
        a0 = __builtin_amdgcn_mfma_f32_16x16x32_bf16(qfh[u], b0l, a0, 0, 0, 0);
        a0 = __builtin_amdgcn_mfma_f32_16x16x32_bf16(qfl[u], b0h, a0, 0, 0, 0);
      }
      // scatter band entries: D col n=l15, row m=q4*4+r; dw = n_w - m_w + 3
      // OOB dh row: skip scatter, logits stay 0 (pre-zeroed)
      #pragma unroll
      for (int r = 0; r < 4; ++r) {
        const int mloc = q4 * 4 + r;
        const int dw = l15 - q4 * 4 - r - 5 + win * 16;
        if (rok && dw >= 0 && dw < 7) lg2[ch][mloc][dh * 7 + dw] = a0[r];
      }
    }
    __builtin_amdgcn_s_setprio(0);
  }
  __syncthreads();

  // ---------- softmax: 16 lanes per pixel, all 256 threads ----------
  {
    const int px = t >> 4, sub = t & 15;
    float mx = -3.0e38f;
    for (int i = sub; i < 49; i += 16)
      mx = fmaxf(mx, lg2[0][px][i] + lg2[1][px][i]);
    mx = fmaxf(mx, __shfl_xor(mx, 1));
    mx = fmaxf(mx, __shfl_xor(mx, 2));
    mx = fmaxf(mx, __shfl_xor(mx, 4));
    mx = fmaxf(mx, __shfl_xor(mx, 8));
    float s = 0.f;
    for (int i = sub; i < 49; i += 16) {
      float v = __expf(lg2[0][px][i] + lg2[1][px][i] - mx);
      lg2[0][px][i] = v;                  // stash exp for pass 3 (same-lane RAW only)
      s += v;
    }
    s += __shfl_xor(s, 1);
    s += __shfl_xor(s, 2);
    s += __shfl_xor(s, 4);
    s += __shfl_xor(s, 8);
    const float inv = 1.f / s;
    for (int i = sub; i < 49; i += 16) {
      const int dh7 = i / 7, dw7 = i - dh7 * 7;
      pb[dh7][px][px + 5 + dw7] = f2bf(lg2[0][px][i] * inv);
    }
  }
  __syncthreads();

  // ---------- phase 2: out[c][m'] = sum_n' v[c][n'] * P[m'][n'] ----------
  // Fully unrolled 4 ct x 7 dh: 28 independent exec-masked loads, 4 independent acc chains.
  const int wo = wbase - 8 + q4 * 8;       // A k-octet start (w coord)
  const bool wok = (wo >= 0) && (wo <= 56);
  f32x4 acc[4];
  #pragma unroll
  for (int i = 0; i < 4; ++i) acc[i] = (f32x4){0.f, 0.f, 0.f, 0.f};
  #pragma unroll
  for (int i = 0; i < 4; ++i) {
    const int ct = wv * 4 + i;             // c-tile (16 channels)
    const u16* vbase = vo + (ct * 16 + l15) * 16384 + wo;  // A: m = l15 (channel)
    #pragma unroll
    for (int dh = 0; dh < 7; ++dh) {
      const int rdh = h + dh - 3;
      const bool rok = (rdh >= 0) && (rdh < 64);
      const int rdhc = rdh < 0 ? 0 : (rdh > 63 ? 63 : rdh);  // clamped address
      const int rp = (b * 64 + rdhc) * 64;
      short8 af = (wok && rok) ? *(const short8*)(vbase + rp) : zf;  // OOB -> zero contribution
      short8 bf_ = *(const short8*)(&pb[dh][l15][q4 * 8]);
      acc[i] = __builtin_amdgcn_mfma_f32_16x16x32_bf16(af, bf_, acc[i], 0, 0, 0);
    }
  }
  #pragma unroll
  for (int i = 0; i < 4; ++i) {
    const int ct = wv * 4 + i;
    // D: row m = channel q4*4+r, col n = pixel l15 -> native [b][c][h][w]
    #pragma unroll
    for (int r = 0; r < 4; ++r)
      out[(b * 256 + ct * 16 + q4 * 4 + r) * 4096 + h * 64 + wbase + l15] = acc[i][r];
  }
}

extern "C" void kernel_launch(void* const* d_in, const int* in_sizes, int n_in,
                              void* d_out, int out_size, void* d_ws, size_t ws_size,
                              hipStream_t stream)
{
  const float* x  = (const float*)d_in[0];
  const float* w1 = (const float*)d_in[1];
  const float* w2 = (const float*)d_in[2];
  const float* w3 = (const float*)d_in[3];
  float* out = (float*)d_out;

  // x hi/lo bf16 split lives in d_out (16 MB); consumed by qkv_gemm, then d_out is
  // fully rewritten by attn phase 2 (stream-ordered).
  u16* XTh = (u16*)d_out;
  u16* XTl = XTh + 4194304;

  char* ws = (char*)d_ws;
  u16* qh_ = (u16*)ws;                     // 8 MB bf16 hi(q), pixel-major [pix][c]
  u16* ql_ = (u16*)(ws + (8u  << 20));     // 8 MB bf16 lo(q)
  u16* kh_ = (u16*)(ws + (16u << 20));     // 8 MB bf16 hi(k)
  u16* kl_ = (u16*)(ws + (24u << 20));     // 8 MB bf16 lo(k)
  u16* vo  = (u16*)(ws + (32u << 20));     // 8 MB bf16 v, c-major [c][pix]
  u16* Wh  = (u16*)(ws + (40u << 20));     // 384 KB
  u16* Wl  = Wh + 196608;                  // 384 KB

  split_in<<<dim3(64, 4, 4), 256, 0, stream>>>(x, XTh, XTl);
  wsplit<<<192, 256, 0, stream>>>(w1, w2, w3, Wh, Wl);
  qkv_gemm<<<dim3(128, 2, 3), 256, 0, stream>>>(XTh, XTl, Wh, Wl, qh_, ql_, kh_, kl_, vo);
  attn<<<dim3(1024), 256, 0, stream>>>(qh_, ql_, kh_, kl_, vo, out);
}

// Round 3
// 136.673 us; speedup vs baseline: 1.0898x; 1.0898x over previous
//
#include <hip/hip_runtime.h>

typedef unsigned short u16;
typedef unsigned int u32;
typedef __attribute__((ext_vector_type(8))) short short8;
typedef __attribute__((ext_vector_type(4))) float f32x4;

__device__ __forceinline__ float bf2f(u16 h){ return __builtin_bit_cast(float, ((u32)h) << 16); }
__device__ __forceinline__ u16 f2bf(float f){
  u32 u = __builtin_bit_cast(u32, f);
  u32 r = u + 0x7fffu + ((u >> 16) & 1u);
  return (u16)(r >> 16);
}
// byte offset of channel-octet `co` of tile-pixel `px` in a swizzled [px][256ch] bf16 LDS tile
__device__ __forceinline__ int swzb(int px, int co){
  return px * 512 + ((co * 16) ^ ((((px & 7) ^ ((px >> 3) * 3)) & 7) << 4));
}

// ------- Kernel 0: x fp32 [b][c][hw] -> XTh/XTl bf16 hi/lo split, pixel-major [pix][c] -------
__global__ __launch_bounds__(256) void split_in(const float* __restrict__ x,
                                                u16* __restrict__ XTh,
                                                u16* __restrict__ XTl)
{
  __shared__ float tile[64 * 68];
  int t = threadIdx.x;
  int hw0 = blockIdx.x * 64, c0 = blockIdx.y * 64, b = blockIdx.z;
  {
    int cl = t >> 2, seg = (t & 3) * 16;
    const float* src = x + (b * 256 + c0 + cl) * 4096 + hw0 + seg;
    float4 v0 = ((const float4*)src)[0];
    float4 v1 = ((const float4*)src)[1];
    float4 v2 = ((const float4*)src)[2];
    float4 v3 = ((const float4*)src)[3];
    float* d = tile + cl * 68 + seg;
    ((float4*)d)[0] = v0; ((float4*)d)[1] = v1;
    ((float4*)d)[2] = v2; ((float4*)d)[3] = v3;
  }
  __syncthreads();
  {
    int hwl = t >> 2, cs = (t & 3) * 16;
    u32 ph[8], pl[8];
    #pragma unroll
    for (int e = 0; e < 8; ++e) {
      float v0 = tile[(cs + 2 * e) * 68 + hwl];
      float v1 = tile[(cs + 2 * e + 1) * 68 + hwl];
      u16 h0 = f2bf(v0), h1 = f2bf(v1);
      u16 l0 = f2bf(v0 - bf2f(h0)), l1 = f2bf(v1 - bf2f(h1));
      ph[e] = (u32)h0 | ((u32)h1 << 16);
      pl[e] = (u32)l0 | ((u32)l1 << 16);
    }
    int off = (b * 4096 + hw0 + hwl) * 256 + c0 + cs;
    *(uint4*)(XTh + off)     = make_uint4(ph[0], ph[1], ph[2], ph[3]);
    *(uint4*)(XTh + off + 8) = make_uint4(ph[4], ph[5], ph[6], ph[7]);
    *(uint4*)(XTl + off)     = make_uint4(pl[0], pl[1], pl[2], pl[3]);
    *(uint4*)(XTl + off + 8) = make_uint4(pl[4], pl[5], pl[6], pl[7]);
  }
}

// ------- Kernel 0b: w1|w2|w3 fp32 [o][c] -> Wh/Wl bf16 hi/lo -------
__global__ __launch_bounds__(256) void wsplit(const float* __restrict__ w1,
                                              const float* __restrict__ w2,
                                              const float* __restrict__ w3,
                                              u16* __restrict__ Wh,
                                              u16* __restrict__ Wl)
{
  int i = (blockIdx.x * 256 + threadIdx.x) * 4;
  int z = i >> 16, off = i & 65535;
  const float* w = (z == 0) ? w1 : ((z == 1) ? w2 : w3);
  float4 v = *(const float4*)(w + off);
  u16 h0 = f2bf(v.x), h1 = f2bf(v.y), h2 = f2bf(v.z), h3 = f2bf(v.w);
  u16 l0 = f2bf(v.x - bf2f(h0)), l1 = f2bf(v.y - bf2f(h1));
  u16 l2 = f2bf(v.z - bf2f(h2)), l3 = f2bf(v.w - bf2f(h3));
  uint2 hv; hv.x = (u32)h0 | ((u32)h1 << 16); hv.y = (u32)h2 | ((u32)h3 << 16);
  uint2 lv; lv.x = (u32)l0 | ((u32)l1 << 16); lv.y = (u32)l2 | ((u32)l3 << 16);
  *(uint2*)(Wh + i) = hv;
  *(uint2*)(Wl + i) = lv;
}

// ------- Kernel 1: q/k via 3-pass split-bf16 MFMA -> hi/lo bf16 pixel-major;
//         v via 1-pass -> bf16 pixel-major. grid (128, 2, 3). -------
#define LSTR 40
__global__ __launch_bounds__(256) void qkv_gemm(const u16* __restrict__ XTh,
                                                const u16* __restrict__ XTl,
                                                const u16* __restrict__ Wh,
                                                const u16* __restrict__ Wl,
                                                u16* __restrict__ qh_, u16* __restrict__ ql_,
                                                u16* __restrict__ kh_, u16* __restrict__ kl_,
                                                u16* __restrict__ vo)
{
  __shared__ u16 lAh[128 * LSTR];
  __shared__ u16 lBh[128 * LSTR];
  __shared__ u16 lAl[128 * LSTR];
  __shared__ u16 lBl[128 * LSTR];
  int z = blockIdx.z;
  int t = threadIdx.x;
  int lane = t & 63, wv = t >> 6;
  int ln15 = lane & 15, q = lane >> 4;
  int pix0 = blockIdx.x * 128;
  int o0 = blockIdx.y * 128;
  int pw = (wv >> 1) * 64, ow = (wv & 1) * 64;
  f32x4 acc[4][4];
  #pragma unroll
  for (int i = 0; i < 4; ++i)
    #pragma unroll
    for (int j = 0; j < 4; ++j)
      acc[i][j] = (f32x4){0.f, 0.f, 0.f, 0.f};

  int srow = t >> 1;
  int sseg = (t & 1) * 16;
  const u16* gAh = XTh + (pix0 + srow) * 256 + sseg;
  const u16* gAl = XTl + (pix0 + srow) * 256 + sseg;
  const u16* gBh = Wh + z * 65536 + (o0 + srow) * 256 + sseg;
  const u16* gBl = Wl + z * 65536 + (o0 + srow) * 256 + sseg;
  u16* sAh = lAh + srow * LSTR + sseg;
  u16* sAl = lAl + srow * LSTR + sseg;
  u16* sBh = lBh + srow * LSTR + sseg;
  u16* sBl = lBl + srow * LSTR + sseg;

  for (int kc = 0; kc < 256; kc += 32) {
    uint4 ah0 = *(const uint4*)(gAh + kc);
    uint4 ah1 = *(const uint4*)(gAh + kc + 8);
    uint4 bh0 = *(const uint4*)(gBh + kc);
    uint4 bh1 = *(const uint4*)(gBh + kc + 8);
    uint4 al0 = make_uint4(0,0,0,0), al1 = make_uint4(0,0,0,0);
    uint4 bl0 = make_uint4(0,0,0,0), bl1 = make_uint4(0,0,0,0);
    if (z < 2) {
      al0 = *(const uint4*)(gAl + kc);
      al1 = *(const uint4*)(gAl + kc + 8);
      bl0 = *(const uint4*)(gBl + kc);
      bl1 = *(const uint4*)(gBl + kc + 8);
    }
    __syncthreads();
    *(uint4*)sAh = ah0; *(uint4*)(sAh + 8) = ah1;
    *(uint4*)sBh = bh0; *(uint4*)(sBh + 8) = bh1;
    if (z < 2) {
      *(uint4*)sAl = al0; *(uint4*)(sAl + 8) = al1;
      *(uint4*)sBl = bl0; *(uint4*)(sBl + 8) = bl1;
    }
    __syncthreads();
    short8 afh[4], bfh[4];
    #pragma unroll
    for (int i = 0; i < 4; ++i)
      afh[i] = *(const short8*)(lAh + (pw + i * 16 + ln15) * LSTR + q * 8);
    #pragma unroll
    for (int j = 0; j < 4; ++j)
      bfh[j] = *(const short8*)(lBh + (ow + j * 16 + ln15) * LSTR + q * 8);
    #pragma unroll
    for (int i = 0; i < 4; ++i)
      #pragma unroll
      for (int j = 0; j < 4; ++j)
        acc[i][j] = __builtin_amdgcn_mfma_f32_16x16x32_bf16(afh[i], bfh[j], acc[i][j], 0, 0, 0);
    if (z < 2) {
      short8 afl[4], bfl[4];
      #pragma unroll
      for (int i = 0; i < 4; ++i)
        afl[i] = *(const short8*)(lAl + (pw + i * 16 + ln15) * LSTR + q * 8);
      #pragma unroll
      for (int j = 0; j < 4; ++j)
        bfl[j] = *(const short8*)(lBl + (ow + j * 16 + ln15) * LSTR + q * 8);
      #pragma unroll
      for (int i = 0; i < 4; ++i)
        #pragma unroll
        for (int j = 0; j < 4; ++j) {
          acc[i][j] = __builtin_amdgcn_mfma_f32_16x16x32_bf16(afh[i], bfl[j], acc[i][j], 0, 0, 0);
          acc[i][j] = __builtin_amdgcn_mfma_f32_16x16x32_bf16(afl[i], bfh[j], acc[i][j], 0, 0, 0);
        }
    }
  }

  // D: m(pixel) = pw + i*16 + q*4 + r, n(o) = ow + j*16 + ln15
  if (z == 2) {
    // v: pixel-major [pix][c], hi only (same layout as q/k hi)
    #pragma unroll
    for (int i = 0; i < 4; ++i) {
      #pragma unroll
      for (int r = 0; r < 4; ++r) {
        int pix = pix0 + pw + i * 16 + q * 4 + r;
        int ob = o0 + ow + ln15;
        #pragma unroll
        for (int j = 0; j < 4; ++j)
          vo[pix * 256 + ob + j * 16] = f2bf(acc[i][j][r]);
      }
    }
  } else {
    u16* dsth = (z == 0) ? qh_ : kh_;
    u16* dstl = (z == 0) ? ql_ : kl_;
    #pragma unroll
    for (int i = 0; i < 4; ++i) {
      #pragma unroll
      for (int r = 0; r < 4; ++r) {
        int pix = pix0 + pw + i * 16 + q * 4 + r;
        int ob = o0 + ow + ln15;
        #pragma unroll
        for (int j = 0; j < 4; ++j) {
          float vv = acc[i][j][r];
          u16 hh = f2bf(vv);
          u16 ll = f2bf(vv - bf2f(hh));
          dsth[pix * 256 + ob + j * 16] = hh;
          dstl[pix * 256 + ob + j * 16] = ll;
        }
      }
    }
  }
}

// ------- Kernel 2: banded-MFMA local attention, all operands staged via coalesced
// global->LDS copies (swizzled pixel-major tiles). Block = quarter row (16 q-px).
// k tile: 24 px (w in [wbase-4, wbase+20)), hi+lo, 24 KB, per-dh restage w/ T14 prefetch.
// v tile: 32 px (w in [wbase-8, wbase+24)), 16 KB, reuses the same buffer; MFMA A-fragment
// transpose done by 8x ds_read_u16 gathers (LDS is banked -> divergence free there). -------
__global__ __launch_bounds__(256, 4) void attn(const u16* __restrict__ qh_,
                                               const u16* __restrict__ ql_,
                                               const u16* __restrict__ kh_,
                                               const u16* __restrict__ kl_,
                                               const u16* __restrict__ vo,
                                               float* __restrict__ out)
{
  __shared__ u16 kst[12288];             // 24576 B: k hi @0, k lo @+12288B; q hi @0/lo @+8192B; v @0 (16 KB)
  __shared__ float lg2[2][16][57];       // 7296 B
  __shared__ u16 pb[7][16][40];          // 8960 B   (total 40832 <= 40960 -> 4 blocks/CU)

  const int t = threadIdx.x;
  const int lane = t & 63, wv = t >> 6;
  const int l15 = lane & 15, q4 = lane >> 4;
  const int bid = ((int)blockIdx.x & 7) * 128 + ((int)blockIdx.x >> 3);  // XCD-bijective
  const int quarter = bid & 3;
  const int row = bid >> 2;               // b*64 + h
  const int b = row >> 6, h = row & 63;
  const int wbase = quarter * 16;
  char* sk = (char*)kst;

  for (int i = t; i < 2 * 16 * 57; i += 256) ((float*)lg2)[i] = 0.f;
  for (int i = t; i < 2240; i += 256) ((u32*)pb)[i] = 0u;

  // ---------- q stage (coalesced 16 KB) ----------
  #pragma unroll
  for (int it = 0; it < 2; ++it) {
    const int s = t + it * 256;                 // 0..511
    const int px = s >> 5, co = s & 31;
    const int g = (row * 64 + wbase + px) * 256 + co * 8;
    const uint4 vh = *(const uint4*)(qh_ + g);
    const uint4 vl = *(const uint4*)(ql_ + g);
    const int off = swzb(px, co);
    *(uint4*)(sk + off) = vh;
    *(uint4*)(sk + 8192 + off) = vl;
  }

  const int ch = wv >> 1, win = wv & 1;          // wave -> (c-half, n-window)
  uint4 ph[3], pl[3];
  // k prefetch for dh=0 (flies during barrier + q-frag reads)
  {
    const int rdh0 = h - 3;
    const int rdhc = rdh0 < 0 ? 0 : rdh0;
    const int rp = (b * 64 + rdhc) * 64;
    #pragma unroll
    for (int it = 0; it < 3; ++it) {
      const int s = t + it * 256;
      const int px = s >> 5, co = s & 31;
      const int w = wbase - 4 + px;
      const int wc = w < 0 ? 0 : (w > 63 ? 63 : w);
      const int g = (rp + wc) * 256 + co * 8;
      uint4 vh = *(const uint4*)(kh_ + g);
      uint4 vl = *(const uint4*)(kl_ + g);
      const bool zz = (w < 0) | (w > 63);
      ph[it].x = zz ? 0u : vh.x; ph[it].y = zz ? 0u : vh.y; ph[it].z = zz ? 0u : vh.z; ph[it].w = zz ? 0u : vh.w;
      pl[it].x = zz ? 0u : vl.x; pl[it].y = zz ? 0u : vl.y; pl[it].z = zz ? 0u : vl.z; pl[it].w = zz ? 0u : vl.w;
    }
  }
  __syncthreads();

  // q fragments from LDS
  short8 qfh[4], qfl[4];
  #pragma unroll
  for (int u = 0; u < 4; ++u) {
    const int co = (ch * 4 + u) * 4 + q4;
    const int off = swzb(l15, co);
    qfh[u] = *(const short8*)(sk + off);
    qfl[u] = *(const short8*)(sk + 8192 + off);
  }

  // ---------- phase 1: logits ----------
  // B-column tile index for this wave's window (junk cols never scattered; clamped)
  const int tidx = win ? (l15 + 12 > 23 ? 23 : l15 + 12) : (l15 - 4 < 0 ? 0 : l15 - 4);
  #pragma unroll 1
  for (int dh = 0; dh < 7; ++dh) {
    __syncthreads();                      // previous compute done reading kst
    #pragma unroll
    for (int it = 0; it < 3; ++it) {      // WRITEK
      const int s = t + it * 256;
      const int px = s >> 5, co = s & 31;
      const int off = swzb(px, co);
      *(uint4*)(sk + off) = ph[it];
      *(uint4*)(sk + 12288 + off) = pl[it];
    }
    if (dh < 6) {                         // LOADK(dh+1): flies during compute
      const int rdh1 = h + dh - 2;
      const int rdhc = rdh1 < 0 ? 0 : (rdh1 > 63 ? 63 : rdh1);
      const int rp = (b * 64 + rdhc) * 64;
      #pragma unroll
      for (int it = 0; it < 3; ++it) {
        const int s = t + it * 256;
        const int px = s >> 5, co = s & 31;
        const int w = wbase - 4 + px;
        const int wc = w < 0 ? 0 : (w > 63 ? 63 : w);
        const int g = (rp + wc) * 256 + co * 8;
        uint4 vh = *(const uint4*)(kh_ + g);
        uint4 vl = *(const uint4*)(kl_ + g);
        const bool zz = (w < 0) | (w > 63);
        ph[it].x = zz ? 0u : vh.x; ph[it].y = zz ? 0u : vh.y; ph[it].z = zz ? 0u : vh.z; ph[it].w = zz ? 0u : vh.w;
        pl[it].x = zz ? 0u : vl.x; pl[it].y = zz ? 0u : vl.y; pl[it].z = zz ? 0u : vl.z; pl[it].w = zz ? 0u : vl.w;
      }
    }
    __syncthreads();                      // staged tile visible
    const int rdh = h + dh - 3;
    const bool rok = (rdh >= 0) && (rdh < 64);
    f32x4 a0 = {0.f, 0.f, 0.f, 0.f};
    f32x4 a1 = {0.f, 0.f, 0.f, 0.f};     // split chains for MFMA ILP
    #pragma unroll
    for (int u = 0; u < 4; ++u) {
      const int co = (ch * 4 + u) * 4 + q4;
      const int off = swzb(tidx, co);
      const short8 bh_ = *(const short8*)(sk + off);
      const short8 bl_ = *(const short8*)(sk + 12288 + off);
      a0 = __builtin_amdgcn_mfma_f32_16x16x32_bf16(qfh[u], bh_, a0, 0, 0, 0);
      a1 = __builtin_amdgcn_mfma_f32_16x16x32_bf16(qfh[u], bl_, a1, 0, 0, 0);
      a0 = __builtin_amdgcn_mfma_f32_16x16x32_bf16(qfl[u], bh_, a0, 0, 0, 0);
    }
    // scatter band entries: D col n=l15, row m=q4*4+r; dw = n_w - m_w + 3
    #pragma unroll
    for (int r = 0; r < 4; ++r) {
      const int mloc = q4 * 4 + r;
      const int dw = l15 - mloc - 5 + win * 16;
      if (rok && dw >= 0 && dw < 7) lg2[ch][mloc][dh * 7 + dw] = a0[r] + a1[r];
    }
  }

  // v prefetch for dh=0 (flies during softmax)
  uint4 pv[4];
  {
    const int rdh0 = h - 3;
    const bool rok2 = rdh0 >= 0;
    const int rdhc = rdh0 < 0 ? 0 : rdh0;
    const int rp = (b * 64 + rdhc) * 64;
    #pragma unroll
    for (int it = 0; it < 4; ++it) {
      const int s = t + it * 256;
      const int px = s >> 5, co = s & 31;
      const int w = wbase - 8 + px;
      const int wc = w < 0 ? 0 : (w > 63 ? 63 : w);
      const int g = (rp + wc) * 256 + co * 8;
      uint4 vv = *(const uint4*)(vo + g);
      const bool zz = (!rok2) | (w < 0) | (w > 63);
      pv[it].x = zz ? 0u : vv.x; pv[it].y = zz ? 0u : vv.y; pv[it].z = zz ? 0u : vv.z; pv[it].w = zz ? 0u : vv.w;
    }
  }
  __syncthreads();

  // ---------- softmax: 16 lanes per pixel ----------
  {
    const int px = t >> 4, sub = t & 15;
    float mx = -3.0e38f;
    for (int i = sub; i < 49; i += 16)
      mx = fmaxf(mx, lg2[0][px][i] + lg2[1][px][i]);
    mx = fmaxf(mx, __shfl_xor(mx, 1));
    mx = fmaxf(mx, __shfl_xor(mx, 2));
    mx = fmaxf(mx, __shfl_xor(mx, 4));
    mx = fmaxf(mx, __shfl_xor(mx, 8));
    float s = 0.f;
    for (int i = sub; i < 49; i += 16) {
      float v = __expf(lg2[0][px][i] + lg2[1][px][i] - mx);
      lg2[0][px][i] = v;                  // stash exp (same-lane RAW only)
      s += v;
    }
    s += __shfl_xor(s, 1);
    s += __shfl_xor(s, 2);
    s += __shfl_xor(s, 4);
    s += __shfl_xor(s, 8);
    const float inv = 1.f / s;
    for (int i = sub; i < 49; i += 16) {
      const int dh7 = i / 7, dw7 = i - dh7 * 7;
      pb[dh7][px][px + 5 + dw7] = f2bf(lg2[0][px][i] * inv);
    }
  }

  // ---------- phase 2: out[c][m'] = sum_n' v[c][n'] * P[m'][n'] ----------
  f32x4 acc[4];
  #pragma unroll
  for (int i = 0; i < 4; ++i) acc[i] = (f32x4){0.f, 0.f, 0.f, 0.f};
  #pragma unroll 1
  for (int dh = 0; dh < 7; ++dh) {
    __syncthreads();                      // kst free (phase1 / prev iter done)
    #pragma unroll
    for (int it = 0; it < 4; ++it) {      // WRITEV
      const int s = t + it * 256;
      const int px = s >> 5, co = s & 31;
      *(uint4*)(sk + swzb(px, co)) = pv[it];
    }
    if (dh < 6) {                         // LOADV(dh+1)
      const int rdh1 = h + dh - 2;
      const bool rok2 = (rdh1 >= 0) && (rdh1 < 64);
      const int rdhc = rdh1 < 0 ? 0 : (rdh1 > 63 ? 63 : rdh1);
      const int rp = (b * 64 + rdhc) * 64;
      #pragma unroll
      for (int it = 0; it < 4; ++it) {
        const int s = t + it * 256;
        const int px = s >> 5, co = s & 31;
        const int w = wbase - 8 + px;
        const int wc = w < 0 ? 0 : (w > 63 ? 63 : w);
        const int g = (rp + wc) * 256 + co * 8;
        uint4 vv = *(const uint4*)(vo + g);
        const bool zz = (!rok2) | (w < 0) | (w > 63);
        pv[it].x = zz ? 0u : vv.x; pv[it].y = zz ? 0u : vv.y; pv[it].z = zz ? 0u : vv.z; pv[it].w = zz ? 0u : vv.w;
      }
    }
    __syncthreads();                      // tile visible
    #pragma unroll
    for (int i = 0; i < 4; ++i) {
      const int c = wv * 64 + i * 16 + l15;      // A: m = channel
      short8 af;
      u16* afp = (u16*)&af;
      #pragma unroll
      for (int e = 0; e < 8; ++e) {              // gather transpose from LDS
        const int px = q4 * 8 + e;               // k-dim = neighbor pixel
        const int off = swzb(px, c >> 3) + (c & 7) * 2;
        afp[e] = *(const u16*)(sk + off);
      }
      const short8 bf_ = *(const short8*)(&pb[dh][l15][q4 * 8]);
      acc[i] = __builtin_amdgcn_mfma_f32_16x16x32_bf16(af, bf_, acc[i], 0, 0, 0);
    }
  }
  #pragma unroll
  for (int i = 0; i < 4; ++i) {
    const int ct = wv * 4 + i;
    // D: row m = channel q4*4+r, col n = pixel l15 -> native [b][c][h][w]
    #pragma unroll
    for (int r = 0; r < 4; ++r)
      out[(b * 256 + ct * 16 + q4 * 4 + r) * 4096 + h * 64 + wbase + l15] = acc[i][r];
  }
}

extern "C" void kernel_launch(void* const* d_in, const int* in_sizes, int n_in,
                              void* d_out, int out_size, void* d_ws, size_t ws_size,
                              hipStream_t stream)
{
  const float* x  = (const float*)d_in[0];
  const float* w1 = (const float*)d_in[1];
  const float* w2 = (const float*)d_in[2];
  const float* w3 = (const float*)d_in[3];
  float* out = (float*)d_out;

  // x hi/lo bf16 split lives in d_out (16 MB); consumed by qkv_gemm, then d_out is
  // fully rewritten by attn phase 2 (stream-ordered).
  u16* XTh = (u16*)d_out;
  u16* XTl = XTh + 4194304;

  char* ws = (char*)d_ws;
  u16* qh_ = (u16*)ws;                     // 8 MB bf16 hi(q), pixel-major [pix][c]
  u16* ql_ = (u16*)(ws + (8u  << 20));     // 8 MB bf16 lo(q)
  u16* kh_ = (u16*)(ws + (16u << 20));     // 8 MB bf16 hi(k)
  u16* kl_ = (u16*)(ws + (24u << 20));     // 8 MB bf16 lo(k)
  u16* vo  = (u16*)(ws + (32u << 20));     // 8 MB bf16 v, pixel-major [pix][c]
  u16* Wh  = (u16*)(ws + (40u << 20));     // 384 KB
  u16* Wl  = Wh + 196608;                  // 384 KB

  split_in<<<dim3(64, 4, 4), 256, 0, stream>>>(x, XTh, XTl);
  wsplit<<<192, 256, 0, stream>>>(w1, w2, w3, Wh, Wl);
  qkv_gemm<<<dim3(128, 2, 3), 256, 0, stream>>>(XTh, XTl, Wh, Wl, qh_, ql_, kh_, kl_, vo);
  attn<<<dim3(1024), 256, 0, stream>>>(qh_, ql_, kh_, kl_, vo, out);
}

// Round 4
// 135.583 us; speedup vs baseline: 1.0985x; 1.0080x over previous
//
#include <hip/hip_runtime.h>

typedef unsigned short u16;
typedef unsigned int u32;
typedef __attribute__((ext_vector_type(8))) short short8;
typedef __attribute__((ext_vector_type(4))) float f32x4;

__device__ __forceinline__ float bf2f(u16 h){ return __builtin_bit_cast(float, ((u32)h) << 16); }
__device__ __forceinline__ u16 f2bf(float f){
  u32 u = __builtin_bit_cast(u32, f);
  u32 r = u + 0x7fffu + ((u >> 16) & 1u);
  return (u16)(r >> 16);
}
// byte offset of channel-octet `co` of tile-pixel `px` in a swizzled [px][256ch] bf16 LDS tile
__device__ __forceinline__ int swzb(int px, int co){
  return px * 512 + ((co * 16) ^ ((((px & 7) ^ ((px >> 3) * 3)) & 7) << 4));
}

// ------- Kernel 0: x fp32 [b][c][hw] -> XTh/XTl bf16 hi/lo split, pixel-major [pix][c] -------
__global__ __launch_bounds__(256) void split_in(const float* __restrict__ x,
                                                u16* __restrict__ XTh,
                                                u16* __restrict__ XTl)
{
  __shared__ float tile[64 * 68];
  int t = threadIdx.x;
  int hw0 = blockIdx.x * 64, c0 = blockIdx.y * 64, b = blockIdx.z;
  {
    int cl = t >> 2, seg = (t & 3) * 16;
    const float* src = x + (b * 256 + c0 + cl) * 4096 + hw0 + seg;
    float4 v0 = ((const float4*)src)[0];
    float4 v1 = ((const float4*)src)[1];
    float4 v2 = ((const float4*)src)[2];
    float4 v3 = ((const float4*)src)[3];
    float* d = tile + cl * 68 + seg;
    ((float4*)d)[0] = v0; ((float4*)d)[1] = v1;
    ((float4*)d)[2] = v2; ((float4*)d)[3] = v3;
  }
  __syncthreads();
  {
    int hwl = t >> 2, cs = (t & 3) * 16;
    u32 ph[8], pl[8];
    #pragma unroll
    for (int e = 0; e < 8; ++e) {
      float v0 = tile[(cs + 2 * e) * 68 + hwl];
      float v1 = tile[(cs + 2 * e + 1) * 68 + hwl];
      u16 h0 = f2bf(v0), h1 = f2bf(v1);
      u16 l0 = f2bf(v0 - bf2f(h0)), l1 = f2bf(v1 - bf2f(h1));
      ph[e] = (u32)h0 | ((u32)h1 << 16);
      pl[e] = (u32)l0 | ((u32)l1 << 16);
    }
    int off = (b * 4096 + hw0 + hwl) * 256 + c0 + cs;
    *(uint4*)(XTh + off)     = make_uint4(ph[0], ph[1], ph[2], ph[3]);
    *(uint4*)(XTh + off + 8) = make_uint4(ph[4], ph[5], ph[6], ph[7]);
    *(uint4*)(XTl + off)     = make_uint4(pl[0], pl[1], pl[2], pl[3]);
    *(uint4*)(XTl + off + 8) = make_uint4(pl[4], pl[5], pl[6], pl[7]);
  }
}

// ------- Kernel 0b: w1|w2|w3 fp32 [o][c] -> Wh/Wl bf16 hi/lo -------
__global__ __launch_bounds__(256) void wsplit(const float* __restrict__ w1,
                                              const float* __restrict__ w2,
                                              const float* __restrict__ w3,
                                              u16* __restrict__ Wh,
                                              u16* __restrict__ Wl)
{
  int i = (blockIdx.x * 256 + threadIdx.x) * 4;
  int z = i >> 16, off = i & 65535;
  const float* w = (z == 0) ? w1 : ((z == 1) ? w2 : w3);
  float4 v = *(const float4*)(w + off);
  u16 h0 = f2bf(v.x), h1 = f2bf(v.y), h2 = f2bf(v.z), h3 = f2bf(v.w);
  u16 l0 = f2bf(v.x - bf2f(h0)), l1 = f2bf(v.y - bf2f(h1));
  u16 l2 = f2bf(v.z - bf2f(h2)), l3 = f2bf(v.w - bf2f(h3));
  uint2 hv; hv.x = (u32)h0 | ((u32)h1 << 16); hv.y = (u32)h2 | ((u32)h3 << 16);
  uint2 lv; lv.x = (u32)l0 | ((u32)l1 << 16); lv.y = (u32)l2 | ((u32)l3 << 16);
  *(uint2*)(Wh + i) = hv;
  *(uint2*)(Wl + i) = lv;
}

// ------- Kernel 1: q/k via 3-pass split-bf16 MFMA -> hi/lo bf16 pixel-major;
//         v via 1-pass -> bf16 pixel-major. grid (128, 2, 3).
//         Staging via global_load_lds(16B): linear [128][32]u16 LDS tiles, source-chunk
//         XOR-swizzle c=(L&3)^((L>>3)&3) (involution), same XOR on ds_read side -> 2-way
//         bank aliasing (free). No register round-trip. -------
__global__ __launch_bounds__(256) void qkv_gemm(const u16* __restrict__ XTh,
                                                const u16* __restrict__ XTl,
                                                const u16* __restrict__ Wh,
                                                const u16* __restrict__ Wl,
                                                u16* __restrict__ qh_, u16* __restrict__ ql_,
                                                u16* __restrict__ kh_, u16* __restrict__ kl_,
                                                u16* __restrict__ vo)
{
  __shared__ u16 lAh[128 * 32];
  __shared__ u16 lBh[128 * 32];
  __shared__ u16 lAl[128 * 32];
  __shared__ u16 lBl[128 * 32];
  const int z = blockIdx.z;
  const int t = threadIdx.x;
  const int lane = t & 63, wv = t >> 6;
  const int ln15 = lane & 15, q = lane >> 4;
  const int pix0 = blockIdx.x * 128;
  const int o0 = blockIdx.y * 128;
  const int pw = (wv >> 1) * 64, ow = (wv & 1) * 64;
  f32x4 acc[4][4];
  #pragma unroll
  for (int i = 0; i < 4; ++i)
    #pragma unroll
    for (int j = 0; j < 4; ++j)
      acc[i][j] = (f32x4){0.f, 0.f, 0.f, 0.f};

  // staging geometry: wave wv stages rows [wv*32, wv*32+32) of each tile in 2 slices of 16 rows.
  // lane L -> row-in-slice = L>>2, linear chunkpos = L&3; global chunk fetched = (L&3)^((L>>3)&3).
  const int Lr = lane >> 2;
  const int cswz = (lane & 3) ^ ((lane >> 3) & 3);
  const int r0 = wv * 32 + Lr;          // slice 0 row
  const int r1 = wv * 32 + 16 + Lr;     // slice 1 row
  // per-lane global element offsets (u16 units) for the two slices
  const int gA0 = (pix0 + r0) * 256 + cswz * 8;
  const int gA1 = (pix0 + r1) * 256 + cswz * 8;
  const int gB0 = z * 65536 + (o0 + r0) * 256 + cswz * 8;
  const int gB1 = z * 65536 + (o0 + r1) * 256 + cswz * 8;
  // wave-uniform LDS slice bases (u16 units)
  const int s0 = wv * 1024;             // = (wv*32 rows) * 32
  const int s1 = wv * 1024 + 512;
  // read-side chunk swizzle (u16 units)
  const int qsw = (q ^ ((ln15 >> 1) & 3)) * 8;

  for (int kc = 0; kc < 256; kc += 32) {
    __syncthreads();                    // previous K-step done reading LDS
    __builtin_amdgcn_global_load_lds((const u32*)(XTh + gA0 + kc), (u32*)(lAh + s0), 16, 0, 0);
    __builtin_amdgcn_global_load_lds((const u32*)(XTh + gA1 + kc), (u32*)(lAh + s1), 16, 0, 0);
    __builtin_amdgcn_global_load_lds((const u32*)(Wh  + gB0 + kc), (u32*)(lBh + s0), 16, 0, 0);
    __builtin_amdgcn_global_load_lds((const u32*)(Wh  + gB1 + kc), (u32*)(lBh + s1), 16, 0, 0);
    if (z < 2) {
      __builtin_amdgcn_global_load_lds((const u32*)(XTl + gA0 + kc), (u32*)(lAl + s0), 16, 0, 0);
      __builtin_amdgcn_global_load_lds((const u32*)(XTl + gA1 + kc), (u32*)(lAl + s1), 16, 0, 0);
      __builtin_amdgcn_global_load_lds((const u32*)(Wl  + gB0 + kc), (u32*)(lBl + s0), 16, 0, 0);
      __builtin_amdgcn_global_load_lds((const u32*)(Wl  + gB1 + kc), (u32*)(lBl + s1), 16, 0, 0);
    }
    __syncthreads();                    // vmcnt drained at barrier -> tiles visible
    short8 afh[4], bfh[4];
    #pragma unroll
    for (int i = 0; i < 4; ++i)
      afh[i] = *(const short8*)(lAh + (pw + i * 16 + ln15) * 32 + qsw);
    #pragma unroll
    for (int j = 0; j < 4; ++j)
      bfh[j] = *(const short8*)(lBh + (ow + j * 16 + ln15) * 32 + qsw);
    #pragma unroll
    for (int i = 0; i < 4; ++i)
      #pragma unroll
      for (int j = 0; j < 4; ++j)
        acc[i][j] = __builtin_amdgcn_mfma_f32_16x16x32_bf16(afh[i], bfh[j], acc[i][j], 0, 0, 0);
    if (z < 2) {
      short8 afl[4], bfl[4];
      #pragma unroll
      for (int i = 0; i < 4; ++i)
        afl[i] = *(const short8*)(lAl + (pw + i * 16 + ln15) * 32 + qsw);
      #pragma unroll
      for (int j = 0; j < 4; ++j)
        bfl[j] = *(const short8*)(lBl + (ow + j * 16 + ln15) * 32 + qsw);
      #pragma unroll
      for (int i = 0; i < 4; ++i)
        #pragma unroll
        for (int j = 0; j < 4; ++j) {
          acc[i][j] = __builtin_amdgcn_mfma_f32_16x16x32_bf16(afh[i], bfl[j], acc[i][j], 0, 0, 0);
          acc[i][j] = __builtin_amdgcn_mfma_f32_16x16x32_bf16(afl[i], bfh[j], acc[i][j], 0, 0, 0);
        }
    }
  }

  // D: m(pixel) = pw + i*16 + q*4 + r, n(o) = ow + j*16 + ln15
  if (z == 2) {
    // v: pixel-major [pix][c], hi only (same layout as q/k hi)
    #pragma unroll
    for (int i = 0; i < 4; ++i) {
      #pragma unroll
      for (int r = 0; r < 4; ++r) {
        int pix = pix0 + pw + i * 16 + q * 4 + r;
        int ob = o0 + ow + ln15;
        #pragma unroll
        for (int j = 0; j < 4; ++j)
          vo[pix * 256 + ob + j * 16] = f2bf(acc[i][j][r]);
      }
    }
  } else {
    u16* dsth = (z == 0) ? qh_ : kh_;
    u16* dstl = (z == 0) ? ql_ : kl_;
    #pragma unroll
    for (int i = 0; i < 4; ++i) {
      #pragma unroll
      for (int r = 0; r < 4; ++r) {
        int pix = pix0 + pw + i * 16 + q * 4 + r;
        int ob = o0 + ow + ln15;
        #pragma unroll
        for (int j = 0; j < 4; ++j) {
          float vv = acc[i][j][r];
          u16 hh = f2bf(vv);
          u16 ll = f2bf(vv - bf2f(hh));
          dsth[pix * 256 + ob + j * 16] = hh;
          dstl[pix * 256 + ob + j * 16] = ll;
        }
      }
    }
  }
}

// ------- Kernel 2: banded-MFMA local attention, all operands staged via coalesced
// global->LDS copies (swizzled pixel-major tiles). Block = quarter row (16 q-px).
// k tile: 24 px (w in [wbase-4, wbase+20)), hi+lo, 24 KB, per-dh restage w/ T14 prefetch.
// v tile: 32 px (w in [wbase-8, wbase+24)), 16 KB, reuses the same buffer; MFMA A-fragment
// transpose done by 8x ds_read_u16 gathers (LDS is banked -> divergence free there). -------
__global__ __launch_bounds__(256, 4) void attn(const u16* __restrict__ qh_,
                                               const u16* __restrict__ ql_,
                                               const u16* __restrict__ kh_,
                                               const u16* __restrict__ kl_,
                                               const u16* __restrict__ vo,
                                               float* __restrict__ out)
{
  __shared__ u16 kst[12288];             // 24576 B: k hi @0, k lo @+12288B; q hi @0/lo @+8192B; v @0 (16 KB)
  __shared__ float lg2[2][16][57];       // 7296 B
  __shared__ u16 pb[7][16][40];          // 8960 B   (total 40832 <= 40960 -> 4 blocks/CU)

  const int t = threadIdx.x;
  const int lane = t & 63, wv = t >> 6;
  const int l15 = lane & 15, q4 = lane >> 4;
  const int bid = ((int)blockIdx.x & 7) * 128 + ((int)blockIdx.x >> 3);  // XCD-bijective
  const int quarter = bid & 3;
  const int row = bid >> 2;               // b*64 + h
  const int b = row >> 6, h = row & 63;
  const int wbase = quarter * 16;
  char* sk = (char*)kst;

  for (int i = t; i < 2 * 16 * 57; i += 256) ((float*)lg2)[i] = 0.f;
  for (int i = t; i < 2240; i += 256) ((u32*)pb)[i] = 0u;

  // ---------- q stage (coalesced 16 KB) ----------
  #pragma unroll
  for (int it = 0; it < 2; ++it) {
    const int s = t + it * 256;                 // 0..511
    const int px = s >> 5, co = s & 31;
    const int g = (row * 64 + wbase + px) * 256 + co * 8;
    const uint4 vh = *(const uint4*)(qh_ + g);
    const uint4 vl = *(const uint4*)(ql_ + g);
    const int off = swzb(px, co);
    *(uint4*)(sk + off) = vh;
    *(uint4*)(sk + 8192 + off) = vl;
  }

  const int ch = wv >> 1, win = wv & 1;          // wave -> (c-half, n-window)
  uint4 ph[3], pl[3];
  // k prefetch for dh=0 (flies during barrier + q-frag reads)
  {
    const int rdh0 = h - 3;
    const int rdhc = rdh0 < 0 ? 0 : rdh0;
    const int rp = (b * 64 + rdhc) * 64;
    #pragma unroll
    for (int it = 0; it < 3; ++it) {
      const int s = t + it * 256;
      const int px = s >> 5, co = s & 31;
      const int w = wbase - 4 + px;
      const int wc = w < 0 ? 0 : (w > 63 ? 63 : w);
      const int g = (rp + wc) * 256 + co * 8;
      uint4 vh = *(const uint4*)(kh_ + g);
      uint4 vl = *(const uint4*)(kl_ + g);
      const bool zz = (w < 0) | (w > 63);
      ph[it].x = zz ? 0u : vh.x; ph[it].y = zz ? 0u : vh.y; ph[it].z = zz ? 0u : vh.z; ph[it].w = zz ? 0u : vh.w;
      pl[it].x = zz ? 0u : vl.x; pl[it].y = zz ? 0u : vl.y; pl[it].z = zz ? 0u : vl.z; pl[it].w = zz ? 0u : vl.w;
    }
  }
  __syncthreads();

  // q fragments from LDS
  short8 qfh[4], qfl[4];
  #pragma unroll
  for (int u = 0; u < 4; ++u) {
    const int co = (ch * 4 + u) * 4 + q4;
    const int off = swzb(l15, co);
    qfh[u] = *(const short8*)(sk + off);
    qfl[u] = *(const short8*)(sk + 8192 + off);
  }

  // ---------- phase 1: logits ----------
  // B-column tile index for this wave's window (junk cols never scattered; clamped)
  const int tidx = win ? (l15 + 12 > 23 ? 23 : l15 + 12) : (l15 - 4 < 0 ? 0 : l15 - 4);
  #pragma unroll 1
  for (int dh = 0; dh < 7; ++dh) {
    __syncthreads();                      // previous compute done reading kst
    #pragma unroll
    for (int it = 0; it < 3; ++it) {      // WRITEK
      const int s = t + it * 256;
      const int px = s >> 5, co = s & 31;
      const int off = swzb(px, co);
      *(uint4*)(sk + off) = ph[it];
      *(uint4*)(sk + 12288 + off) = pl[it];
    }
    if (dh < 6) {                         // LOADK(dh+1): flies during compute
      const int rdh1 = h + dh - 2;
      const int rdhc = rdh1 < 0 ? 0 : (rdh1 > 63 ? 63 : rdh1);
      const int rp = (b * 64 + rdhc) * 64;
      #pragma unroll
      for (int it = 0; it < 3; ++it) {
        const int s = t + it * 256;
        const int px = s >> 5, co = s & 31;
        const int w = wbase - 4 + px;
        const int wc = w < 0 ? 0 : (w > 63 ? 63 : w);
        const int g = (rp + wc) * 256 + co * 8;
        uint4 vh = *(const uint4*)(kh_ + g);
        uint4 vl = *(const uint4*)(kl_ + g);
        const bool zz = (w < 0) | (w > 63);
        ph[it].x = zz ? 0u : vh.x; ph[it].y = zz ? 0u : vh.y; ph[it].z = zz ? 0u : vh.z; ph[it].w = zz ? 0u : vh.w;
        pl[it].x = zz ? 0u : vl.x; pl[it].y = zz ? 0u : vl.y; pl[it].z = zz ? 0u : vl.z; pl[it].w = zz ? 0u : vl.w;
      }
    }
    __syncthreads();                      // staged tile visible
    const int rdh = h + dh - 3;
    const bool rok = (rdh >= 0) && (rdh < 64);
    f32x4 a0 = {0.f, 0.f, 0.f, 0.f};
    f32x4 a1 = {0.f, 0.f, 0.f, 0.f};     // split chains for MFMA ILP
    #pragma unroll
    for (int u = 0; u < 4; ++u) {
      const int co = (ch * 4 + u) * 4 + q4;
      const int off = swzb(tidx, co);
      const short8 bh_ = *(const short8*)(sk + off);
      const short8 bl_ = *(const short8*)(sk + 12288 + off);
      a0 = __builtin_amdgcn_mfma_f32_16x16x32_bf16(qfh[u], bh_, a0, 0, 0, 0);
      a1 = __builtin_amdgcn_mfma_f32_16x16x32_bf16(qfh[u], bl_, a1, 0, 0, 0);
      a0 = __builtin_amdgcn_mfma_f32_16x16x32_bf16(qfl[u], bh_, a0, 0, 0, 0);
    }
    // scatter band entries: D col n=l15, row m=q4*4+r; dw = n_w - m_w + 3
    #pragma unroll
    for (int r = 0; r < 4; ++r) {
      const int mloc = q4 * 4 + r;
      const int dw = l15 - mloc - 5 + win * 16;
      if (rok && dw >= 0 && dw < 7) lg2[ch][mloc][dh * 7 + dw] = a0[r] + a1[r];
    }
  }

  // v prefetch for dh=0 (flies during softmax)
  uint4 pv[4];
  {
    const int rdh0 = h - 3;
    const bool rok2 = rdh0 >= 0;
    const int rdhc = rdh0 < 0 ? 0 : rdh0;
    const int rp = (b * 64 + rdhc) * 64;
    #pragma unroll
    for (int it = 0; it < 4; ++it) {
      const int s = t + it * 256;
      const int px = s >> 5, co = s & 31;
      const int w = wbase - 8 + px;
      const int wc = w < 0 ? 0 : (w > 63 ? 63 : w);
      const int g = (rp + wc) * 256 + co * 8;
      uint4 vv = *(const uint4*)(vo + g);
      const bool zz = (!rok2) | (w < 0) | (w > 63);
      pv[it].x = zz ? 0u : vv.x; pv[it].y = zz ? 0u : vv.y; pv[it].z = zz ? 0u : vv.z; pv[it].w = zz ? 0u : vv.w;
    }
  }
  __syncthreads();

  // ---------- softmax: 16 lanes per pixel ----------
  {
    const int px = t >> 4, sub = t & 15;
    float mx = -3.0e38f;
    for (int i = sub; i < 49; i += 16)
      mx = fmaxf(mx, lg2[0][px][i] + lg2[1][px][i]);
    mx = fmaxf(mx, __shfl_xor(mx, 1));
    mx = fmaxf(mx, __shfl_xor(mx, 2));
    mx = fmaxf(mx, __shfl_xor(mx, 4));
    mx = fmaxf(mx, __shfl_xor(mx, 8));
    float s = 0.f;
    for (int i = sub; i < 49; i += 16) {
      float v = __expf(lg2[0][px][i] + lg2[1][px][i] - mx);
      lg2[0][px][i] = v;                  // stash exp (same-lane RAW only)
      s += v;
    }
    s += __shfl_xor(s, 1);
    s += __shfl_xor(s, 2);
    s += __shfl_xor(s, 4);
    s += __shfl_xor(s, 8);
    const float inv = 1.f / s;
    for (int i = sub; i < 49; i += 16) {
      const int dh7 = i / 7, dw7 = i - dh7 * 7;
      pb[dh7][px][px + 5 + dw7] = f2bf(lg2[0][px][i] * inv);
    }
  }

  // ---------- phase 2: out[c][m'] = sum_n' v[c][n'] * P[m'][n'] ----------
  f32x4 acc[4];
  #pragma unroll
  for (int i = 0; i < 4; ++i) acc[i] = (f32x4){0.f, 0.f, 0.f, 0.f};
  #pragma unroll 1
  for (int dh = 0; dh < 7; ++dh) {
    __syncthreads();                      // kst free (phase1 / prev iter done)
    #pragma unroll
    for (int it = 0; it < 4; ++it) {      // WRITEV
      const int s = t + it * 256;
      const int px = s >> 5, co = s & 31;
      *(uint4*)(sk + swzb(px, co)) = pv[it];
    }
    if (dh < 6) {                         // LOADV(dh+1)
      const int rdh1 = h + dh - 2;
      const bool rok2 = (rdh1 >= 0) && (rdh1 < 64);
      const int rdhc = rdh1 < 0 ? 0 : (rdh1 > 63 ? 63 : rdh1);
      const int rp = (b * 64 + rdhc) * 64;
      #pragma unroll
      for (int it = 0; it < 4; ++it) {
        const int s = t + it * 256;
        const int px = s >> 5, co = s & 31;
        const int w = wbase - 8 + px;
        const int wc = w < 0 ? 0 : (w > 63 ? 63 : w);
        const int g = (rp + wc) * 256 + co * 8;
        uint4 vv = *(const uint4*)(vo + g);
        const bool zz = (!rok2) | (w < 0) | (w > 63);
        pv[it].x = zz ? 0u : vv.x; pv[it].y = zz ? 0u : vv.y; pv[it].z = zz ? 0u : vv.z; pv[it].w = zz ? 0u : vv.w;
      }
    }
    __syncthreads();                      // tile visible
    #pragma unroll
    for (int i = 0; i < 4; ++i) {
      const int c = wv * 64 + i * 16 + l15;      // A: m = channel
      short8 af;
      u16* afp = (u16*)&af;
      #pragma unroll
      for (int e = 0; e < 8; ++e) {              // gather transpose from LDS
        const int px = q4 * 8 + e;               // k-dim = neighbor pixel
        const int off = swzb(px, c >> 3) + (c & 7) * 2;
        afp[e] = *(const u16*)(sk + off);
      }
      const short8 bf_ = *(const short8*)(&pb[dh][l15][q4 * 8]);
      acc[i] = __builtin_amdgcn_mfma_f32_16x16x32_bf16(af, bf_, acc[i], 0, 0, 0);
    }
  }
  #pragma unroll
  for (int i = 0; i < 4; ++i) {
    const int ct = wv * 4 + i;
    // D: row m = channel q4*4+r, col n = pixel l15 -> native [b][c][h][w]
    #pragma unroll
    for (int r = 0; r < 4; ++r)
      out[(b * 256 + ct * 16 + q4 * 4 + r) * 4096 + h * 64 + wbase + l15] = acc[i][r];
  }
}

extern "C" void kernel_launch(void* const* d_in, const int* in_sizes, int n_in,
                              void* d_out, int out_size, void* d_ws, size_t ws_size,
                              hipStream_t stream)
{
  const float* x  = (const float*)d_in[0];
  const float* w1 = (const float*)d_in[1];
  const float* w2 = (const float*)d_in[2];
  const float* w3 = (const float*)d_in[3];
  float* out = (float*)d_out;

  // x hi/lo bf16 split lives in d_out (16 MB); consumed by qkv_gemm, then d_out is
  // fully rewritten by attn phase 2 (stream-ordered).
  u16* XTh = (u16*)d_out;
  u16* XTl = XTh + 4194304;

  char* ws = (char*)d_ws;
  u16* qh_ = (u16*)ws;                     // 8 MB bf16 hi(q), pixel-major [pix][c]
  u16* ql_ = (u16*)(ws + (8u  << 20));     // 8 MB bf16 lo(q)
  u16* kh_ = (u16*)(ws + (16u << 20));     // 8 MB bf16 hi(k)
  u16* kl_ = (u16*)(ws + (24u << 20));     // 8 MB bf16 lo(k)
  u16* vo  = (u16*)(ws + (32u << 20));     // 8 MB bf16 v, pixel-major [pix][c]
  u16* Wh  = (u16*)(ws + (40u << 20));     // 384 KB
  u16* Wl  = Wh + 196608;                  // 384 KB

  split_in<<<dim3(64, 4, 4), 256, 0, stream>>>(x, XTh, XTl);
  wsplit<<<192, 256, 0, stream>>>(w1, w2, w3, Wh, Wl);
  qkv_gemm<<<dim3(128, 2, 3), 256, 0, stream>>>(XTh, XTl, Wh, Wl, qh_, ql_, kh_, kl_, vo);
  attn<<<dim3(1024), 256, 0, stream>>>(qh_, ql_, kh_, kl_, vo, out);
}